// Round 8
// baseline (278.355 us; speedup 1.0000x reference)
//
#include <hip/hip_runtime.h>
#include <math.h>

#define Bn 8
#define Tn 256
#define COREn 16512
#define SDn   33025
#define NBLK  256

typedef __attribute__((ext_vector_type(8))) short short8;
typedef __attribute__((ext_vector_type(4))) short short4v;
typedef __attribute__((ext_vector_type(4))) float floatx4;

#define MFMA16(a,b,c) __builtin_amdgcn_mfma_f32_16x16x32_bf16(a,b,c,0,0,0)

static __device__ __forceinline__ unsigned short f2bf(float f) {
  unsigned int u = __float_as_uint(f);
  return (unsigned short)((u + 0x7FFFu + ((u >> 16) & 1u)) >> 16);
}
static __device__ __forceinline__ float bf2f(unsigned short h) {
  return __uint_as_float((unsigned int)h << 16);
}
static __device__ __forceinline__ short8 ldwfrag(const float* p) {
  float4 a = *(const float4*)p;
  float4 b = *(const float4*)(p + 4);
  short8 r;
  r[0] = (short)f2bf(a.x); r[1] = (short)f2bf(a.y);
  r[2] = (short)f2bf(a.z); r[3] = (short)f2bf(a.w);
  r[4] = (short)f2bf(b.x); r[5] = (short)f2bf(b.y);
  r[6] = (short)f2bf(b.z); r[7] = (short)f2bf(b.w);
  return r;
}
static __device__ __forceinline__ void ld8(const float* p, float* v) {
  float4 a = *(const float4*)p, b = *(const float4*)(p + 4);
  v[0]=a.x; v[1]=a.y; v[2]=a.z; v[3]=a.w; v[4]=b.x; v[5]=b.y; v[6]=b.z; v[7]=b.w;
}

// ---------------- LDS phase union ----------------
struct ProjS { unsigned short xs[16][136]; float tl[32][33]; };
struct AttnS {
  unsigned short xs[16][136];
  unsigned short Ssc[4][16][40];
  float Obuf[4][16][68];
  float Z0s[128];
  float denw[4][16];
  float denz[16];
  float dinv[16];
};
struct FfS { unsigned short xa[16][136]; unsigned short hs[16][136]; float os[16][132]; };
union SmU { ProjS p; AttnS a; FfS f; };

// ---------------- grid barrier (device-scope) ----------------
static __device__ __forceinline__ void gridbar(unsigned* cnt) {
  __syncthreads();
  if (threadIdx.x == 0) {
    __threadfence();   // release all prior writes to device scope
    __hip_atomic_fetch_add(cnt, 1u, __ATOMIC_ACQ_REL, __HIP_MEMORY_SCOPE_AGENT);
    while (__hip_atomic_load(cnt, __ATOMIC_ACQUIRE, __HIP_MEMORY_SCOPE_AGENT) < (unsigned)NBLK)
      __builtin_amdgcn_s_sleep(8);
    __threadfence();   // acquire: invalidate stale cached lines
  }
  __syncthreads();
}

// ---------------- proj epilogue (verified) ----------------
static __device__ __forceinline__ void proj_epilogue(
    int by, int g0, int b, int t0l, int n0, int n1, int quad,
    floatx4 acc0, floatx4 acc1,
    unsigned short* Kb, unsigned short* Kt,
    unsigned short* Qb, unsigned short* Vt,
    unsigned short* skipb, const float* scb) {
  if (by == 0) {
    short4v kt0, kt1;
#pragma unroll
    for (int j = 0; j < 4; j++) {
      int row = quad * 4 + j;
      float e0 = acc0[j] > 0.f ? acc0[j] + 1.f : expf(acc0[j]);
      float e1 = acc1[j] > 0.f ? acc1[j] + 1.f : expf(acc1[j]);
      Kb[(size_t)(g0 + row) * 128 + n0] = f2bf(e0);
      Kb[(size_t)(g0 + row) * 128 + n1] = f2bf(e1);
      kt0[j] = (short)f2bf(e0); kt1[j] = (short)f2bf(e1);
    }
    *(short4v*)(Kt + (size_t)(b * 128 + n0) * 256 + t0l + quad * 4) = kt0;
    *(short4v*)(Kt + (size_t)(b * 128 + n1) * 256 + t0l + quad * 4) = kt1;
  } else if (by == 1) {
#pragma unroll
    for (int j = 0; j < 4; j++) {
      int row = quad * 4 + j;
      float e0 = acc0[j] > 0.f ? acc0[j] + 1.f : expf(acc0[j]);
      float e1 = acc1[j] > 0.f ? acc1[j] + 1.f : expf(acc1[j]);
      Qb[(size_t)(g0 + row) * 128 + n0] = f2bf(e0);
      Qb[(size_t)(g0 + row) * 128 + n1] = f2bf(e1);
    }
  } else if (by == 2) {
    short4v v0, v1;
#pragma unroll
    for (int j = 0; j < 4; j++) { v0[j] = (short)f2bf(acc0[j]); v1[j] = (short)f2bf(acc1[j]); }
    *(short4v*)(Vt + (size_t)(b * 128 + n0) * 256 + t0l + quad * 4) = v0;
    *(short4v*)(Vt + (size_t)(b * 128 + n1) * 256 + t0l + quad * 4) = v1;
  } else {
    float sb0 = scb[n0], sb1 = scb[n1];
#pragma unroll
    for (int j = 0; j < 4; j++) {
      int row = quad * 4 + j;
      skipb[(size_t)(g0 + row) * 128 + n0] = f2bf(acc0[j] + sb0);
      skipb[(size_t)(g0 + row) * 128 + n1] = f2bf(acc1[j] + sb1);
    }
  }
}

// ---------------- stage units ----------------
static __device__ void proj0_unit(
    SmU& sm, int tid, int tile, int by,
    const float* z, const float* state,
    const float* Wk, const float* Wq, const float* Wv, const float* scw,
    const float* lnw, const float* lnb, const float* scb,
    unsigned short* Kb0, unsigned short* Qb0,
    unsigned short* Kt0, unsigned short* Vt0, unsigned short* skip0) {
  const int lane = tid & 63, wv = tid >> 6, lm = lane & 15, quad = lane >> 4;
  const int g0 = tile * 16;
  const int r = tid >> 4, c0 = (tid & 15) * 8;
  const int g = g0 + r, b = g >> 8, t = g & 255;
  const int n0 = wv * 32 + lm, n1 = n0 + 16;

  float v[8], pv[8];
  const float* zr = z + ((size_t)t * Bn + b) * 128;
  ld8(zr + c0, v);
  ld8(zr + (c0 ^ 64), pv);
  const float* W = by == 0 ? Wk : by == 1 ? Wq : by == 2 ? Wv : scw;
  short8 bA[4], bB[4];
#pragma unroll
  for (int kc = 0; kc < 4; kc++) {
    bA[kc] = ldwfrag(W + (size_t)n0 * 128 + kc * 32 + quad * 8);
    bB[kc] = ldwfrag(W + (size_t)n1 * 128 + kc * 32 + quad * 8);
  }
  float pos = state[(size_t)b * SDn + SDn - 1] + (float)t;
#pragma unroll
  for (int i = 0; i < 8; i++) {
    int jj = (c0 + i) & 63;
    float ang = pos * expf((float)jj * -0.14391156831212787f);
    float sn = sinf(ang), cs = cosf(ang);
    v[i] = (c0 < 64) ? (v[i] * cs - pv[i] * sn) : (v[i] * cs + pv[i] * sn);
  }
  float sm_ = 0.f, sq = 0.f;
#pragma unroll
  for (int i = 0; i < 8; i++) { sm_ += v[i]; sq += v[i] * v[i]; }
  for (int d = 8; d; d >>= 1) { sm_ += __shfl_xor(sm_, d, 16); sq += __shfl_xor(sq, d, 16); }
  float mean = sm_ * (1.f / 128.f);
  float rstd = rsqrtf(sq * (1.f / 128.f) - mean * mean + 1e-5f);
  short8 xv;
#pragma unroll
  for (int i = 0; i < 8; i++)
    xv[i] = (short)f2bf((v[i] - mean) * rstd * lnw[c0 + i] + lnb[c0 + i]);
  __syncthreads();                      // previous xs readers done
  *(short8*)&sm.p.xs[r][c0] = xv;
  __syncthreads();

  const int bb = g0 >> 8, t0l = g0 & 255;
  floatx4 a0 = {0.f,0.f,0.f,0.f}, a1 = {0.f,0.f,0.f,0.f};
#pragma unroll
  for (int kc = 0; kc < 4; kc++) {
    short8 a = *(const short8*)&sm.p.xs[lm][kc * 32 + quad * 8];
    a0 = MFMA16(a, bA[kc], a0);
    a1 = MFMA16(a, bB[kc], a1);
  }
  proj_epilogue(by, g0, bb, t0l, n0, n1, quad, a0, a1,
                Kb0, Kt0, Qb0, Vt0, skip0, scb);
}

static __device__ void s0t_unit(SmU& sm, int tid, int id,
    const float* state, unsigned short* S0t) {
  const int b = id >> 1, l = id & 1;
  const float* src = state + (size_t)b * SDn + (size_t)l * COREn;
  unsigned short* dst = S0t + (size_t)(l * 8 + b) * 16384;
  const int r = tid >> 3, c4 = (tid & 7) * 4;
  __syncthreads();
#pragma unroll
  for (int tI = 0; tI < 4; tI++)
    for (int tJ = 0; tJ < 4; tJ++) {
      int i0 = tI * 32, j0 = tJ * 32;
#pragma unroll
      for (int q = 0; q < 4; q++)
        sm.p.tl[r][c4 + q] = src[(size_t)(i0 + r) * 128 + j0 + c4 + q];
      __syncthreads();
      short4v o;
#pragma unroll
      for (int q = 0; q < 4; q++) o[q] = (short)f2bf(sm.p.tl[c4 + q][r]);
      *(short4v*)(dst + (size_t)(j0 + r) * 128 + i0 + c4) = o;
      __syncthreads();
    }
}

static __device__ void attn_unit(
    SmU& sm, int tid, int unit, int l,
    const unsigned short* Kb, const unsigned short* Qb,
    const unsigned short* Vt, const unsigned short* S0tl,
    const float* state, unsigned short* attnb) {
  const int lane = tid & 63, wv = tid >> 6, lm = lane & 15, quad = lane >> 4;
  const int tile = unit >> 1, half = unit & 1;
  const int b = tile >> 4, rt = tile & 15, t0 = rt * 16;
  const size_t sb = (size_t)b * SDn + (size_t)l * COREn;

  const int r = tid >> 4, cQ = (tid & 15) * 8;
  short8 qrow = *(const short8*)(Qb + (size_t)(b * 256 + t0 + r) * 128 + cQ);
  float z0v = (tid < 128) ? state[sb + 16384 + tid] : 0.f;

  const int nch = rt / 2 + 1;
  const bool hasA = (wv < nch), hasB = (wv + 4 < nch);
  const int kbA = (hasA ? wv : nch - 1) * 32;
  const int kbB = (hasB ? wv + 4 : nch - 1) * 32;
  short8 KA[8], KB[8], VA[4], VB[4], SF[4];
#pragma unroll
  for (int kc = 0; kc < 4; kc++) {
    KA[kc]     = *(const short8*)(Kb + (size_t)(b * 256 + kbA + lm) * 128 + kc * 32 + quad * 8);
    KA[4 + kc] = *(const short8*)(Kb + (size_t)(b * 256 + kbA + 16 + lm) * 128 + kc * 32 + quad * 8);
    KB[kc]     = *(const short8*)(Kb + (size_t)(b * 256 + kbB + lm) * 128 + kc * 32 + quad * 8);
    KB[4 + kc] = *(const short8*)(Kb + (size_t)(b * 256 + kbB + 16 + lm) * 128 + kc * 32 + quad * 8);
  }
#pragma unroll
  for (int jt = 0; jt < 4; jt++) {
    VA[jt] = *(const short8*)(Vt + (size_t)(b * 128 + half * 64 + jt * 16 + lm) * 256 + kbA + quad * 8);
    VB[jt] = *(const short8*)(Vt + (size_t)(b * 128 + half * 64 + jt * 16 + lm) * 256 + kbB + quad * 8);
    SF[jt] = *(const short8*)(S0tl + (size_t)b * 16384 +
                  (size_t)(half * 64 + jt * 16 + lm) * 128 + wv * 32 + quad * 8);
  }

  *(short8*)&sm.a.xs[r][cQ] = qrow;
  if (tid < 128) sm.a.Z0s[tid] = z0v;
  __syncthreads();

  { float qz = 0.f;
#pragma unroll
    for (int i = 0; i < 8; i++) qz += bf2f(sm.a.xs[r][cQ + i]) * sm.a.Z0s[cQ + i];
    for (int d = 8; d; d >>= 1) qz += __shfl_xor(qz, d, 16);
    if ((tid & 15) == 0) sm.a.denz[r] = qz; }

  floatx4 oacc[4];
#pragma unroll
  for (int jt = 0; jt < 4; jt++) oacc[jt] = floatx4{0.f, 0.f, 0.f, 0.f};
  float dacc[4] = {0.f, 0.f, 0.f, 0.f};

  { floatx4 s0 = {0.f,0.f,0.f,0.f}, s1 = {0.f,0.f,0.f,0.f};
#pragma unroll
    for (int kc = 0; kc < 4; kc++) {
      short8 a = *(const short8*)&sm.a.xs[lm][kc * 32 + quad * 8];
      s0 = MFMA16(a, KA[kc], s0);
      s1 = MFMA16(a, KA[4 + kc], s1);
    }
    const int tau0 = kbA + lm, tau1 = kbA + 16 + lm;
#pragma unroll
    for (int j = 0; j < 4; j++) {
      int m = t0 + quad * 4 + j;
      float v0 = (hasA && tau0 <= m) ? s0[j] : 0.f;
      float v1 = (hasA && tau1 <= m) ? s1[j] : 0.f;
      dacc[j] += v0 + v1;
      sm.a.Ssc[wv][quad * 4 + j][lm]      = f2bf(v0);
      sm.a.Ssc[wv][quad * 4 + j][16 + lm] = f2bf(v1);
    }
    short8 sa = *(const short8*)&sm.a.Ssc[wv][lm][quad * 8];
#pragma unroll
    for (int jt = 0; jt < 4; jt++) oacc[jt] = MFMA16(sa, VA[jt], oacc[jt]);
  }
  { floatx4 s0 = {0.f,0.f,0.f,0.f}, s1 = {0.f,0.f,0.f,0.f};
#pragma unroll
    for (int kc = 0; kc < 4; kc++) {
      short8 a = *(const short8*)&sm.a.xs[lm][kc * 32 + quad * 8];
      s0 = MFMA16(a, KB[kc], s0);
      s1 = MFMA16(a, KB[4 + kc], s1);
    }
    const int tau0 = kbB + lm, tau1 = kbB + 16 + lm;
#pragma unroll
    for (int j = 0; j < 4; j++) {
      int m = t0 + quad * 4 + j;
      float v0 = (hasB && tau0 <= m) ? s0[j] : 0.f;
      float v1 = (hasB && tau1 <= m) ? s1[j] : 0.f;
      dacc[j] += v0 + v1;
      sm.a.Ssc[wv][quad * 4 + j][lm]      = f2bf(v0);
      sm.a.Ssc[wv][quad * 4 + j][16 + lm] = f2bf(v1);
    }
    short8 sa = *(const short8*)&sm.a.Ssc[wv][lm][quad * 8];
#pragma unroll
    for (int jt = 0; jt < 4; jt++) oacc[jt] = MFMA16(sa, VB[jt], oacc[jt]);
  }
  { short8 aq = *(const short8*)&sm.a.xs[lm][wv * 32 + quad * 8];
#pragma unroll
    for (int jt = 0; jt < 4; jt++) oacc[jt] = MFMA16(aq, SF[jt], oacc[jt]); }

#pragma unroll
  for (int j = 0; j < 4; j++)
    for (int d = 8; d; d >>= 1) dacc[j] += __shfl_xor(dacc[j], d, 16);
  if (lm == 0) {
#pragma unroll
    for (int j = 0; j < 4; j++) sm.a.denw[wv][quad * 4 + j] = dacc[j];
  }
#pragma unroll
  for (int jt = 0; jt < 4; jt++)
#pragma unroll
    for (int j = 0; j < 4; j++)
      sm.a.Obuf[wv][quad * 4 + j][jt * 16 + lm] = oacc[jt][j];
  __syncthreads();
  if (tid < 16)
    sm.a.dinv[tid] = 1.f / (sm.a.denz[tid] + sm.a.denw[0][tid] + sm.a.denw[1][tid]
                            + sm.a.denw[2][tid] + sm.a.denw[3][tid] + 1e-5f);
  __syncthreads();
  { int rr = tid >> 4, c = (tid & 15) * 4;
    float di = sm.a.dinv[rr];
    short4v ov;
#pragma unroll
    for (int q = 0; q < 4; q++) {
      float o = sm.a.Obuf[0][rr][c + q] + sm.a.Obuf[1][rr][c + q]
              + sm.a.Obuf[2][rr][c + q] + sm.a.Obuf[3][rr][c + q];
      ov[q] = (short)f2bf(o * di);
    }
    *(short4v*)(attnb + (size_t)(b * 256 + t0 + rr) * 128 + half * 64 + c) = ov; }
}

static __device__ void state_unit(
    int tid, int idx, int l,
    const unsigned short* Kt, const unsigned short* Vt,
    const float* state, float* st_out) {
  const int lane = tid & 63, wv = tid >> 6, lm = lane & 15, quad = lane >> 4;
  const int b = idx >> 4, sub = idx & 15;
  const int i0 = (sub >> 1) * 16, j0 = (sub & 1) * 64;
  const size_t sb = (size_t)b * SDn + (size_t)l * COREn;
  short8 ka[8], vb[8];
#pragma unroll
  for (int kc = 0; kc < 8; kc++) {
    ka[kc] = *(const short8*)(Kt + (size_t)(b * 128 + i0 + lm) * 256 + kc * 32 + quad * 8);
    vb[kc] = *(const short8*)(Vt + (size_t)(b * 128 + j0 + wv * 16 + lm) * 256 + kc * 32 + quad * 8);
  }
  floatx4 acc = {0.f, 0.f, 0.f, 0.f};
#pragma unroll
  for (int kc = 0; kc < 8; kc++) acc = MFMA16(ka[kc], vb[kc], acc);
#pragma unroll
  for (int j = 0; j < 4; j++) {
    size_t off = sb + (size_t)(i0 + quad * 4 + j) * 128 + j0 + wv * 16 + lm;
    st_out[off] = acc[j] + state[off];
  }
  if (j0 == 0) {
    if (tid < 128) {
      int i = tid >> 3, seg = tid & 7;
      const unsigned short* kr = Kt + (size_t)(b * 128 + i0 + i) * 256 + seg * 32;
      float zs = 0.f;
#pragma unroll
      for (int x = 0; x < 4; x++) {
        short8 kv = *(const short8*)(kr + x * 8);
#pragma unroll
        for (int y = 0; y < 8; y++) zs += bf2f((unsigned short)kv[y]);
      }
      for (int d = 4; d; d >>= 1) zs += __shfl_xor(zs, d, 8);
      if (seg == 0) {
        size_t zo = sb + 16384 + i0 + i;
        st_out[zo] = zs + state[zo];
      }
    }
    if (sub == 0 && tid == 0 && l == 0)
      st_out[(size_t)b * SDn + SDn - 1] = state[(size_t)b * SDn + SDn - 1] + 256.f;
  }
}

static __device__ void ffln_unit(
    SmU& sm, int tid, int g0,
    const unsigned short* attnb, const unsigned short* skipb,
    const float* w1, const float* b1, const float* w2, const float* b2,
    const float* lnw1, const float* lnb1, unsigned short* xln1) {
  const int lane = tid & 63, wv = tid >> 6, lm = lane & 15, quad = lane >> 4;
  const int n0 = wv * 32 + lm, n1 = n0 + 16;
  short8 w1A[4], w1B[4], w2A[4], w2B[4];
#pragma unroll
  for (int kc = 0; kc < 4; kc++) {
    w1A[kc] = ldwfrag(w1 + (size_t)n0 * 128 + kc * 32 + quad * 8);
    w1B[kc] = ldwfrag(w1 + (size_t)n1 * 128 + kc * 32 + quad * 8);
    w2A[kc] = ldwfrag(w2 + (size_t)n0 * 128 + kc * 32 + quad * 8);
    w2B[kc] = ldwfrag(w2 + (size_t)n1 * 128 + kc * 32 + quad * 8);
  }
  float bi10 = b1[n0], bi11 = b1[n1], bi20 = b2[n0], bi21 = b2[n1];
  float sk0[4], sk1[4];
#pragma unroll
  for (int j = 0; j < 4; j++) {
    sk0[j] = bf2f(skipb[(size_t)(g0 + quad * 4 + j) * 128 + n0]);
    sk1[j] = bf2f(skipb[(size_t)(g0 + quad * 4 + j) * 128 + n1]);
  }
  { int r = tid >> 4, c = (tid & 15) * 8;
    *(short8*)&sm.f.xa[r][c] = *(const short8*)(attnb + (size_t)(g0 + r) * 128 + c); }
  __syncthreads();

  { floatx4 a0 = {0.f,0.f,0.f,0.f}, a1 = {0.f,0.f,0.f,0.f};
#pragma unroll
    for (int kc = 0; kc < 4; kc++) {
      short8 a = *(const short8*)&sm.f.xa[lm][kc * 32 + quad * 8];
      a0 = MFMA16(a, w1A[kc], a0);
      a1 = MFMA16(a, w1B[kc], a1);
    }
#pragma unroll
    for (int j = 0; j < 4; j++) {
      int row = quad * 4 + j;
      sm.f.hs[row][n0] = f2bf(fmaxf(a0[j] + bi10, 0.f));
      sm.f.hs[row][n1] = f2bf(fmaxf(a1[j] + bi11, 0.f));
    } }
  __syncthreads();
  { floatx4 a0 = {0.f,0.f,0.f,0.f}, a1 = {0.f,0.f,0.f,0.f};
#pragma unroll
    for (int kc = 0; kc < 4; kc++) {
      short8 a = *(const short8*)&sm.f.hs[lm][kc * 32 + quad * 8];
      a0 = MFMA16(a, w2A[kc], a0);
      a1 = MFMA16(a, w2B[kc], a1);
    }
#pragma unroll
    for (int j = 0; j < 4; j++) {
      int row = quad * 4 + j;
      sm.f.os[row][n0] = fmaxf(a0[j] + bi20, 0.f) + sk0[j];
      sm.f.os[row][n1] = fmaxf(a1[j] + bi21, 0.f) + sk1[j];
    } }
  __syncthreads();
  { int r = tid >> 4, c0 = (tid & 15) * 8;
    float v[8];
#pragma unroll
    for (int i = 0; i < 8; i++) v[i] = sm.f.os[r][c0 + i];
    float sm_ = 0.f, sq = 0.f;
#pragma unroll
    for (int i = 0; i < 8; i++) { sm_ += v[i]; sq += v[i] * v[i]; }
    for (int d = 8; d; d >>= 1) { sm_ += __shfl_xor(sm_, d, 16); sq += __shfl_xor(sq, d, 16); }
    float mean = sm_ * (1.f / 128.f);
    float rstd = rsqrtf(sq * (1.f / 128.f) - mean * mean + 1e-5f);
    short8 xv;
#pragma unroll
    for (int i = 0; i < 8; i++)
      xv[i] = (short)f2bf((v[i] - mean) * rstd * lnw1[c0 + i] + lnb1[c0 + i]);
    *(short8*)(xln1 + (size_t)(g0 + r) * 128 + c0) = xv; }
}

static __device__ void proj1_unit(
    SmU& sm, int tid, int tile, int by,
    const unsigned short* xln1,
    const float* Wk1, const float* Wq1, const float* Wv1, const float* scw1,
    const float* scb1,
    unsigned short* Kb1, unsigned short* Qb1,
    unsigned short* Kt1, unsigned short* Vt1, unsigned short* skip1) {
  const int lane = tid & 63, wv = tid >> 6, lm = lane & 15, quad = lane >> 4;
  const int g0 = tile * 16;
  const int n0 = wv * 32 + lm, n1 = n0 + 16;
  const float* W = by == 0 ? Wk1 : by == 1 ? Wq1 : by == 2 ? Wv1 : scw1;
  short8 bA[4], bB[4];
#pragma unroll
  for (int kc = 0; kc < 4; kc++) {
    bA[kc] = ldwfrag(W + (size_t)n0 * 128 + kc * 32 + quad * 8);
    bB[kc] = ldwfrag(W + (size_t)n1 * 128 + kc * 32 + quad * 8);
  }
  int r = tid >> 4, c = (tid & 15) * 8;
  short8 xrow = *(const short8*)(xln1 + (size_t)(g0 + r) * 128 + c);
  __syncthreads();
  *(short8*)&sm.p.xs[r][c] = xrow;
  __syncthreads();
  const int bb = g0 >> 8, t0l = g0 & 255;
  floatx4 a0 = {0.f,0.f,0.f,0.f}, a1 = {0.f,0.f,0.f,0.f};
#pragma unroll
  for (int kc = 0; kc < 4; kc++) {
    short8 a = *(const short8*)&sm.p.xs[lm][kc * 32 + quad * 8];
    a0 = MFMA16(a, bA[kc], a0);
    a1 = MFMA16(a, bB[kc], a1);
  }
  proj_epilogue(by, g0, bb, t0l, n0, n1, quad, a0, a1,
                Kb1, Kt1, Qb1, Vt1, skip1, scb1);
}

static __device__ void ffu_unit(
    SmU& sm, int tid, int g0,
    const unsigned short* attnb, const unsigned short* skipb,
    const float* w1, const float* b1, const float* w2, const float* b2,
    const float* unw, const float* unb, float* yout) {
  const int lane = tid & 63, wv = tid >> 6, lm = lane & 15, quad = lane >> 4;
  const int n0 = wv * 32 + lm, n1 = n0 + 16;
  short8 w1A[4], w1B[4], w2A[4], w2B[4], uA[4], uB[4];
#pragma unroll
  for (int kc = 0; kc < 4; kc++) {
    w1A[kc] = ldwfrag(w1 + (size_t)n0 * 128 + kc * 32 + quad * 8);
    w1B[kc] = ldwfrag(w1 + (size_t)n1 * 128 + kc * 32 + quad * 8);
    w2A[kc] = ldwfrag(w2 + (size_t)n0 * 128 + kc * 32 + quad * 8);
    w2B[kc] = ldwfrag(w2 + (size_t)n1 * 128 + kc * 32 + quad * 8);
    uA[kc]  = ldwfrag(unw + (size_t)n0 * 128 + kc * 32 + quad * 8);
    uB[kc]  = ldwfrag(unw + (size_t)n1 * 128 + kc * 32 + quad * 8);
  }
  float bi10 = b1[n0], bi11 = b1[n1], bi20 = b2[n0], bi21 = b2[n1];
  float u0b = unb[n0], u1b = unb[n1];
  float sk0[4], sk1[4];
#pragma unroll
  for (int j = 0; j < 4; j++) {
    sk0[j] = bf2f(skipb[(size_t)(g0 + quad * 4 + j) * 128 + n0]);
    sk1[j] = bf2f(skipb[(size_t)(g0 + quad * 4 + j) * 128 + n1]);
  }
  { int r = tid >> 4, c = (tid & 15) * 8;
    *(short8*)&sm.f.xa[r][c] = *(const short8*)(attnb + (size_t)(g0 + r) * 128 + c); }
  __syncthreads();

  { floatx4 a0 = {0.f,0.f,0.f,0.f}, a1 = {0.f,0.f,0.f,0.f};
#pragma unroll
    for (int kc = 0; kc < 4; kc++) {
      short8 a = *(const short8*)&sm.f.xa[lm][kc * 32 + quad * 8];
      a0 = MFMA16(a, w1A[kc], a0);
      a1 = MFMA16(a, w1B[kc], a1);
    }
#pragma unroll
    for (int j = 0; j < 4; j++) {
      int row = quad * 4 + j;
      sm.f.hs[row][n0] = f2bf(fmaxf(a0[j] + bi10, 0.f));
      sm.f.hs[row][n1] = f2bf(fmaxf(a1[j] + bi11, 0.f));
    } }
  __syncthreads();
  float o0[4], o1[4];
  { floatx4 a0 = {0.f,0.f,0.f,0.f}, a1 = {0.f,0.f,0.f,0.f};
#pragma unroll
    for (int kc = 0; kc < 4; kc++) {
      short8 a = *(const short8*)&sm.f.hs[lm][kc * 32 + quad * 8];
      a0 = MFMA16(a, w2A[kc], a0);
      a1 = MFMA16(a, w2B[kc], a1);
    }
#pragma unroll
    for (int j = 0; j < 4; j++) {
      o0[j] = fmaxf(a0[j] + bi20, 0.f) + sk0[j];
      o1[j] = fmaxf(a1[j] + bi21, 0.f) + sk1[j];
    } }
  __syncthreads();
#pragma unroll
  for (int j = 0; j < 4; j++) {
    int row = quad * 4 + j;
    sm.f.hs[row][n0] = f2bf(o0[j]);
    sm.f.hs[row][n1] = f2bf(o1[j]);
  }
  __syncthreads();
  { floatx4 a0 = {0.f,0.f,0.f,0.f}, a1 = {0.f,0.f,0.f,0.f};
#pragma unroll
    for (int kc = 0; kc < 4; kc++) {
      short8 a = *(const short8*)&sm.f.hs[lm][kc * 32 + quad * 8];
      a0 = MFMA16(a, uA[kc], a0);
      a1 = MFMA16(a, uB[kc], a1);
    }
#pragma unroll
    for (int j = 0; j < 4; j++) {
      int gg = g0 + quad * 4 + j;
      int bb = gg >> 8, tq = gg & 255;
      yout[(size_t)(tq * Bn + bb) * 128 + n0] = a0[j] + u0b;
      yout[(size_t)(tq * Bn + bb) * 128 + n1] = a1[j] + u1b;
    } }
}

// ---------------- the persistent kernel ----------------
__global__ __launch_bounds__(256, 1) void persistent_kernel(
    const float* z, const float* state,
    const float* Wk, const float* Wq, const float* Wv,
    const float* lnw, const float* lnb,
    const float* w1, const float* b1, const float* w2, const float* b2,
    const float* scw, const float* scb,
    const float* unw, const float* unb,
    float* yout, float* st_out,
    unsigned short* Kb0, unsigned short* Qb0, unsigned short* Kt0, unsigned short* Vt0,
    unsigned short* Kb1, unsigned short* Qb1, unsigned short* Kt1, unsigned short* Vt1,
    unsigned short* skip0, unsigned short* skip1, unsigned short* attnb,
    unsigned short* xln1, unsigned short* S0t, unsigned* bar) {
  __shared__ SmU sm;
  const int tid = threadIdx.x, bx = blockIdx.x;

  // ---- S0: proj l0 (2 units) + S0t (blocks 0..15)
  { int u0 = 2 * bx, u1 = 2 * bx + 1;
    proj0_unit(sm, tid, u0 >> 2, u0 & 3, z, state, Wk, Wq, Wv, scw,
               lnw, lnb, scb, Kb0, Qb0, Kt0, Vt0, skip0);
    proj0_unit(sm, tid, u1 >> 2, u1 & 3, z, state, Wk, Wq, Wv, scw,
               lnw, lnb, scb, Kb0, Qb0, Kt0, Vt0, skip0);
    if (bx < 16) s0t_unit(sm, tid, bx, state, S0t); }
  gridbar(bar + 0);

  // ---- S1: attn l0
  attn_unit(sm, tid, bx, 0, Kb0, Qb0, Vt0, S0t, state, attnb);
  gridbar(bar + 16);

  // ---- S2: ffln l0 | state l0
  if (bx < 128)
    ffln_unit(sm, tid, bx * 16, attnb, skip0, w1, b1, w2, b2,
              lnw + 128, lnb + 128, xln1);
  else
    state_unit(tid, bx - 128, 0, Kt0, Vt0, state, st_out);
  gridbar(bar + 32);

  // ---- S3: proj l1 (2 units)
  { int u0 = 2 * bx, u1 = 2 * bx + 1;
    proj1_unit(sm, tid, u0 >> 2, u0 & 3, xln1,
               Wk + 16384, Wq + 16384, Wv + 16384, scw + 16384, scb + 128,
               Kb1, Qb1, Kt1, Vt1, skip1);
    proj1_unit(sm, tid, u1 >> 2, u1 & 3, xln1,
               Wk + 16384, Wq + 16384, Wv + 16384, scw + 16384, scb + 128,
               Kb1, Qb1, Kt1, Vt1, skip1); }
  gridbar(bar + 48);

  // ---- S4: attn l1
  attn_unit(sm, tid, bx, 1, Kb1, Qb1, Vt1, S0t + (size_t)8 * 16384, state, attnb);
  gridbar(bar + 64);

  // ---- S5: ffu | state l1
  if (bx < 128)
    ffu_unit(sm, tid, bx * 16, attnb, skip1,
             w1 + 16384, b1 + 128, w2 + 16384, b2 + 128, unw, unb, yout);
  else
    state_unit(tid, bx - 128, 1, Kt1, Vt1, state, st_out);
}

// ============================================================ launch
extern "C" void kernel_launch(void* const* d_in, const int* in_sizes, int n_in,
                              void* d_out, int out_size, void* d_ws, size_t ws_size,
                              hipStream_t stream) {
  const float* z       = (const float*)d_in[0];
  const float* state   = (const float*)d_in[1];
  const float* Wk      = (const float*)d_in[2];
  const float* Wq      = (const float*)d_in[3];
  const float* Wv      = (const float*)d_in[4];
  const float* ln_w    = (const float*)d_in[5];
  const float* ln_b    = (const float*)d_in[6];
  const float* ff_w1   = (const float*)d_in[7];
  const float* ff_b1   = (const float*)d_in[8];
  const float* ff_w2   = (const float*)d_in[9];
  const float* ff_b2   = (const float*)d_in[10];
  const float* sc_w    = (const float*)d_in[11];
  const float* sc_b    = (const float*)d_in[12];
  const float* unmap_w = (const float*)d_in[13];
  const float* unmap_b = (const float*)d_in[14];

  float* y_out  = (float*)d_out;                      // (T,B,128)
  float* st_out = y_out + (size_t)Tn * Bn * 128;      // (B,SDn)

  const size_t E = 262144;                            // 2048*128
  unsigned short* Kb0   = (unsigned short*)d_ws;
  unsigned short* Qb0   = Kb0 + E;
  unsigned short* Kt0   = Qb0 + E;
  unsigned short* Vt0   = Kt0 + E;
  unsigned short* Kb1   = Vt0 + E;
  unsigned short* Qb1   = Kb1 + E;
  unsigned short* Kt1   = Qb1 + E;
  unsigned short* Vt1   = Kt1 + E;
  unsigned short* skip0 = Vt1 + E;
  unsigned short* skip1 = skip0 + E;
  unsigned short* attnb = skip1 + E;
  unsigned short* xln1  = attnb + E;
  unsigned short* S0t   = xln1 + E;                   // 2*8*16384 bf16
  unsigned* bar = (unsigned*)(S0t + (size_t)2 * 8 * 16384);

  hipMemsetAsync(bar, 0, 512, stream);                // zero barrier counters

  persistent_kernel<<<NBLK, 256, 0, stream>>>(
      z, state, Wk, Wq, Wv, ln_w, ln_b,
      ff_w1, ff_b1, ff_w2, ff_b2, sc_w, sc_b, unmap_w, unmap_b,
      y_out, st_out,
      Kb0, Qb0, Kt0, Vt0, Kb1, Qb1, Kt1, Vt1,
      skip0, skip1, attnb, xln1, S0t, bar);
}

// Round 9
// 204.013 us; speedup vs baseline: 1.3644x; 1.3644x over previous
//
#include <hip/hip_runtime.h>
#include <math.h>

#define Bn 8
#define Tn 256
#define COREn 16512
#define SDn   33025
#define NBLK  256

typedef __attribute__((ext_vector_type(8))) short short8;
typedef __attribute__((ext_vector_type(4))) short short4v;
typedef __attribute__((ext_vector_type(4))) float floatx4;

#define MFMA16(a,b,c) __builtin_amdgcn_mfma_f32_16x16x32_bf16(a,b,c,0,0,0)

static __device__ __forceinline__ unsigned short f2bf(float f) {
  unsigned int u = __float_as_uint(f);
  return (unsigned short)((u + 0x7FFFu + ((u >> 16) & 1u)) >> 16);
}
static __device__ __forceinline__ float bf2f(unsigned short h) {
  return __uint_as_float((unsigned int)h << 16);
}
static __device__ __forceinline__ short8 ldwfrag(const float* p) {
  float4 a = *(const float4*)p;
  float4 b = *(const float4*)(p + 4);
  short8 r;
  r[0] = (short)f2bf(a.x); r[1] = (short)f2bf(a.y);
  r[2] = (short)f2bf(a.z); r[3] = (short)f2bf(a.w);
  r[4] = (short)f2bf(b.x); r[5] = (short)f2bf(b.y);
  r[6] = (short)f2bf(b.z); r[7] = (short)f2bf(b.w);
  return r;
}
static __device__ __forceinline__ void ld8(const float* p, float* v) {
  float4 a = *(const float4*)p, b = *(const float4*)(p + 4);
  v[0]=a.x; v[1]=a.y; v[2]=a.z; v[3]=a.w; v[4]=b.x; v[5]=b.y; v[6]=b.z; v[7]=b.w;
}

// ---------------- LDS phase union ----------------
struct ProjS { unsigned short xs[16][136]; float tl[32][33]; };
struct AttnS {
  unsigned short xs[16][136];
  unsigned short Ssc[4][16][40];
  float Obuf[4][16][68];
  float Z0s[128];
  float denw[4][16];
  float denz[16];
  float dinv[16];
};
struct FfpS {
  unsigned short xa[16][136];
  unsigned short hs[16][136];
  unsigned short xsl[16][136];
  float os[16][132];
};
union SmU { ProjS p; AttnS a; FfpS f; };

// ---------------- grid barrier: relaxed poll, one acquire at exit ----------------
static __device__ __forceinline__ void gridbar(unsigned* cnt) {
  __syncthreads();
  if (threadIdx.x == 0) {
    __threadfence();                                   // release prior writes
    __hip_atomic_fetch_add(cnt, 1u, __ATOMIC_RELAXED, __HIP_MEMORY_SCOPE_AGENT);
    while (__hip_atomic_load(cnt, __ATOMIC_RELAXED, __HIP_MEMORY_SCOPE_AGENT)
           < (unsigned)NBLK)
      __builtin_amdgcn_s_sleep(1);                     // no cache maintenance per poll
    __threadfence();                                   // single acquire
  }
  __syncthreads();
}

// ---------------- proj epilogue (verified) ----------------
static __device__ __forceinline__ void proj_epilogue(
    int by, int g0, int b, int t0l, int n0, int n1, int quad,
    floatx4 acc0, floatx4 acc1,
    unsigned short* Kb, unsigned short* Kt,
    unsigned short* Qb, unsigned short* Vt,
    unsigned short* skipb, const float* scb) {
  if (by == 0) {
    short4v kt0, kt1;
#pragma unroll
    for (int j = 0; j < 4; j++) {
      int row = quad * 4 + j;
      float e0 = acc0[j] > 0.f ? acc0[j] + 1.f : expf(acc0[j]);
      float e1 = acc1[j] > 0.f ? acc1[j] + 1.f : expf(acc1[j]);
      Kb[(size_t)(g0 + row) * 128 + n0] = f2bf(e0);
      Kb[(size_t)(g0 + row) * 128 + n1] = f2bf(e1);
      kt0[j] = (short)f2bf(e0); kt1[j] = (short)f2bf(e1);
    }
    *(short4v*)(Kt + (size_t)(b * 128 + n0) * 256 + t0l + quad * 4) = kt0;
    *(short4v*)(Kt + (size_t)(b * 128 + n1) * 256 + t0l + quad * 4) = kt1;
  } else if (by == 1) {
#pragma unroll
    for (int j = 0; j < 4; j++) {
      int row = quad * 4 + j;
      float e0 = acc0[j] > 0.f ? acc0[j] + 1.f : expf(acc0[j]);
      float e1 = acc1[j] > 0.f ? acc1[j] + 1.f : expf(acc1[j]);
      Qb[(size_t)(g0 + row) * 128 + n0] = f2bf(e0);
      Qb[(size_t)(g0 + row) * 128 + n1] = f2bf(e1);
    }
  } else if (by == 2) {
    short4v v0, v1;
#pragma unroll
    for (int j = 0; j < 4; j++) { v0[j] = (short)f2bf(acc0[j]); v1[j] = (short)f2bf(acc1[j]); }
    *(short4v*)(Vt + (size_t)(b * 128 + n0) * 256 + t0l + quad * 4) = v0;
    *(short4v*)(Vt + (size_t)(b * 128 + n1) * 256 + t0l + quad * 4) = v1;
  } else {
    float sb0 = scb[n0], sb1 = scb[n1];
#pragma unroll
    for (int j = 0; j < 4; j++) {
      int row = quad * 4 + j;
      skipb[(size_t)(g0 + row) * 128 + n0] = f2bf(acc0[j] + sb0);
      skipb[(size_t)(g0 + row) * 128 + n1] = f2bf(acc1[j] + sb1);
    }
  }
}

// ---------------- stage 0: rotate+LN once, two projections ----------------
static __device__ void proj0_pair(
    SmU& sm, int tid, int bx,
    const float* z, const float* state,
    const float* Wk, const float* Wq, const float* Wv, const float* scw,
    const float* lnw, const float* lnb, const float* scb,
    unsigned short* Kb0, unsigned short* Qb0,
    unsigned short* Kt0, unsigned short* Vt0, unsigned short* skip0) {
  const int lane = tid & 63, wv = tid >> 6, lm = lane & 15, quad = lane >> 4;
  const int tile = bx >> 1, half = bx & 1;
  const int g0 = tile * 16;
  const int r = tid >> 4, c0 = (tid & 15) * 8;
  const int g = g0 + r, b = g >> 8, t = g & 255;
  float v[8], pv[8];
  const float* zr = z + ((size_t)t * Bn + b) * 128;
  ld8(zr + c0, v);
  ld8(zr + (c0 ^ 64), pv);
  float pos = state[(size_t)b * SDn + SDn - 1] + (float)t;
#pragma unroll
  for (int i = 0; i < 8; i++) {
    int jj = (c0 + i) & 63;
    float ang = pos * expf((float)jj * -0.14391156831212787f);
    float sn = sinf(ang), cs = cosf(ang);
    v[i] = (c0 < 64) ? (v[i] * cs - pv[i] * sn) : (v[i] * cs + pv[i] * sn);
  }
  float sm_ = 0.f, sq = 0.f;
#pragma unroll
  for (int i = 0; i < 8; i++) { sm_ += v[i]; sq += v[i] * v[i]; }
  for (int d = 8; d; d >>= 1) { sm_ += __shfl_xor(sm_, d, 16); sq += __shfl_xor(sq, d, 16); }
  float mean = sm_ * (1.f / 128.f);
  float rstd = rsqrtf(sq * (1.f / 128.f) - mean * mean + 1e-5f);
  short8 xv;
#pragma unroll
  for (int i = 0; i < 8; i++)
    xv[i] = (short)f2bf((v[i] - mean) * rstd * lnw[c0 + i] + lnb[c0 + i]);
  *(short8*)&sm.p.xs[r][c0] = xv;
  __syncthreads();

  const int bb = g0 >> 8, t0l = g0 & 255;
  const int n0 = wv * 32 + lm, n1 = n0 + 16;
#pragma unroll
  for (int which = 0; which < 2; which++) {
    const float* W = half == 0 ? (which == 0 ? Wk : Wq)
                               : (which == 0 ? Wv : scw);
    floatx4 a0 = {0.f,0.f,0.f,0.f}, a1 = {0.f,0.f,0.f,0.f};
#pragma unroll
    for (int kc = 0; kc < 4; kc++) {
      short8 a  = *(const short8*)&sm.p.xs[lm][kc * 32 + quad * 8];
      short8 bA = ldwfrag(W + (size_t)n0 * 128 + kc * 32 + quad * 8);
      short8 bB = ldwfrag(W + (size_t)n1 * 128 + kc * 32 + quad * 8);
      a0 = MFMA16(a, bA, a0);
      a1 = MFMA16(a, bB, a1);
    }
    proj_epilogue(half * 2 + which, g0, bb, t0l, n0, n1, quad, a0, a1,
                  Kb0, Kt0, Qb0, Vt0, skip0, scb);
  }
}

static __device__ void s0t_unit(SmU& sm, int tid, int id,
    const float* state, unsigned short* S0t) {
  const int b = id >> 1, l = id & 1;
  const float* src = state + (size_t)b * SDn + (size_t)l * COREn;
  unsigned short* dst = S0t + (size_t)(l * 8 + b) * 16384;
  const int r = tid >> 3, c4 = (tid & 7) * 4;
  __syncthreads();
#pragma unroll
  for (int tI = 0; tI < 4; tI++)
    for (int tJ = 0; tJ < 4; tJ++) {
      int i0 = tI * 32, j0 = tJ * 32;
#pragma unroll
      for (int q = 0; q < 4; q++)
        sm.p.tl[r][c4 + q] = src[(size_t)(i0 + r) * 128 + j0 + c4 + q];
      __syncthreads();
      short4v o;
#pragma unroll
      for (int q = 0; q < 4; q++) o[q] = (short)f2bf(sm.p.tl[c4 + q][r]);
      *(short4v*)(dst + (size_t)(j0 + r) * 128 + i0 + c4) = o;
      __syncthreads();
    }
}

static __device__ void attn_unit(
    SmU& sm, int tid, int unit, int l,
    const unsigned short* Kb, const unsigned short* Qb,
    const unsigned short* Vt, const unsigned short* S0tl,
    const float* state, unsigned short* attnb) {
  const int lane = tid & 63, wv = tid >> 6, lm = lane & 15, quad = lane >> 4;
  const int tile = unit >> 1, half = unit & 1;
  const int b = tile >> 4, rt = tile & 15, t0 = rt * 16;
  const size_t sb = (size_t)b * SDn + (size_t)l * COREn;

  const int r = tid >> 4, cQ = (tid & 15) * 8;
  short8 qrow = *(const short8*)(Qb + (size_t)(b * 256 + t0 + r) * 128 + cQ);
  float z0v = (tid < 128) ? state[sb + 16384 + tid] : 0.f;

  const int nch = rt / 2 + 1;
  const bool hasA = (wv < nch), hasB = (wv + 4 < nch);
  const int kbA = (hasA ? wv : nch - 1) * 32;
  const int kbB = (hasB ? wv + 4 : nch - 1) * 32;
  short8 KA[8], KB[8], VA[4], VB[4], SF[4];
#pragma unroll
  for (int kc = 0; kc < 4; kc++) {
    KA[kc]     = *(const short8*)(Kb + (size_t)(b * 256 + kbA + lm) * 128 + kc * 32 + quad * 8);
    KA[4 + kc] = *(const short8*)(Kb + (size_t)(b * 256 + kbA + 16 + lm) * 128 + kc * 32 + quad * 8);
    KB[kc]     = *(const short8*)(Kb + (size_t)(b * 256 + kbB + lm) * 128 + kc * 32 + quad * 8);
    KB[4 + kc] = *(const short8*)(Kb + (size_t)(b * 256 + kbB + 16 + lm) * 128 + kc * 32 + quad * 8);
  }
#pragma unroll
  for (int jt = 0; jt < 4; jt++) {
    VA[jt] = *(const short8*)(Vt + (size_t)(b * 128 + half * 64 + jt * 16 + lm) * 256 + kbA + quad * 8);
    VB[jt] = *(const short8*)(Vt + (size_t)(b * 128 + half * 64 + jt * 16 + lm) * 256 + kbB + quad * 8);
    SF[jt] = *(const short8*)(S0tl + (size_t)b * 16384 +
                  (size_t)(half * 64 + jt * 16 + lm) * 128 + wv * 32 + quad * 8);
  }

  __syncthreads();                  // previous-phase LDS readers done
  *(short8*)&sm.a.xs[r][cQ] = qrow;
  if (tid < 128) sm.a.Z0s[tid] = z0v;
  __syncthreads();

  { float qz = 0.f;
#pragma unroll
    for (int i = 0; i < 8; i++) qz += bf2f(sm.a.xs[r][cQ + i]) * sm.a.Z0s[cQ + i];
    for (int d = 8; d; d >>= 1) qz += __shfl_xor(qz, d, 16);
    if ((tid & 15) == 0) sm.a.denz[r] = qz; }

  floatx4 oacc[4];
#pragma unroll
  for (int jt = 0; jt < 4; jt++) oacc[jt] = floatx4{0.f, 0.f, 0.f, 0.f};
  float dacc[4] = {0.f, 0.f, 0.f, 0.f};

  { floatx4 s0 = {0.f,0.f,0.f,0.f}, s1 = {0.f,0.f,0.f,0.f};
#pragma unroll
    for (int kc = 0; kc < 4; kc++) {
      short8 a = *(const short8*)&sm.a.xs[lm][kc * 32 + quad * 8];
      s0 = MFMA16(a, KA[kc], s0);
      s1 = MFMA16(a, KA[4 + kc], s1);
    }
    const int tau0 = kbA + lm, tau1 = kbA + 16 + lm;
#pragma unroll
    for (int j = 0; j < 4; j++) {
      int m = t0 + quad * 4 + j;
      float v0 = (hasA && tau0 <= m) ? s0[j] : 0.f;
      float v1 = (hasA && tau1 <= m) ? s1[j] : 0.f;
      dacc[j] += v0 + v1;
      sm.a.Ssc[wv][quad * 4 + j][lm]      = f2bf(v0);
      sm.a.Ssc[wv][quad * 4 + j][16 + lm] = f2bf(v1);
    }
    short8 sa = *(const short8*)&sm.a.Ssc[wv][lm][quad * 8];
#pragma unroll
    for (int jt = 0; jt < 4; jt++) oacc[jt] = MFMA16(sa, VA[jt], oacc[jt]);
  }
  { floatx4 s0 = {0.f,0.f,0.f,0.f}, s1 = {0.f,0.f,0.f,0.f};
#pragma unroll
    for (int kc = 0; kc < 4; kc++) {
      short8 a = *(const short8*)&sm.a.xs[lm][kc * 32 + quad * 8];
      s0 = MFMA16(a, KB[kc], s0);
      s1 = MFMA16(a, KB[4 + kc], s1);
    }
    const int tau0 = kbB + lm, tau1 = kbB + 16 + lm;
#pragma unroll
    for (int j = 0; j < 4; j++) {
      int m = t0 + quad * 4 + j;
      float v0 = (hasB && tau0 <= m) ? s0[j] : 0.f;
      float v1 = (hasB && tau1 <= m) ? s1[j] : 0.f;
      dacc[j] += v0 + v1;
      sm.a.Ssc[wv][quad * 4 + j][lm]      = f2bf(v0);
      sm.a.Ssc[wv][quad * 4 + j][16 + lm] = f2bf(v1);
    }
    short8 sa = *(const short8*)&sm.a.Ssc[wv][lm][quad * 8];
#pragma unroll
    for (int jt = 0; jt < 4; jt++) oacc[jt] = MFMA16(sa, VB[jt], oacc[jt]);
  }
  { short8 aq = *(const short8*)&sm.a.xs[lm][wv * 32 + quad * 8];
#pragma unroll
    for (int jt = 0; jt < 4; jt++) oacc[jt] = MFMA16(aq, SF[jt], oacc[jt]); }

#pragma unroll
  for (int j = 0; j < 4; j++)
    for (int d = 8; d; d >>= 1) dacc[j] += __shfl_xor(dacc[j], d, 16);
  if (lm == 0) {
#pragma unroll
    for (int j = 0; j < 4; j++) sm.a.denw[wv][quad * 4 + j] = dacc[j];
  }
#pragma unroll
  for (int jt = 0; jt < 4; jt++)
#pragma unroll
    for (int j = 0; j < 4; j++)
      sm.a.Obuf[wv][quad * 4 + j][jt * 16 + lm] = oacc[jt][j];
  __syncthreads();
  if (tid < 16)
    sm.a.dinv[tid] = 1.f / (sm.a.denz[tid] + sm.a.denw[0][tid] + sm.a.denw[1][tid]
                            + sm.a.denw[2][tid] + sm.a.denw[3][tid] + 1e-5f);
  __syncthreads();
  { int rr = tid >> 4, c = (tid & 15) * 4;
    float di = sm.a.dinv[rr];
    short4v ov;
#pragma unroll
    for (int q = 0; q < 4; q++) {
      float o = sm.a.Obuf[0][rr][c + q] + sm.a.Obuf[1][rr][c + q]
              + sm.a.Obuf[2][rr][c + q] + sm.a.Obuf[3][rr][c + q];
      ov[q] = (short)f2bf(o * di);
    }
    *(short4v*)(attnb + (size_t)(b * 256 + t0 + rr) * 128 + half * 64 + c) = ov; }
}

static __device__ void state_unit(
    int tid, int idx, int l,
    const unsigned short* Kt, const unsigned short* Vt,
    const float* state, float* st_out) {
  const int lane = tid & 63, wv = tid >> 6, lm = lane & 15, quad = lane >> 4;
  const int b = idx >> 4, sub = idx & 15;
  const int i0 = (sub >> 1) * 16, j0 = (sub & 1) * 64;
  const size_t sb = (size_t)b * SDn + (size_t)l * COREn;
  short8 ka[8], vb[8];
#pragma unroll
  for (int kc = 0; kc < 8; kc++) {
    ka[kc] = *(const short8*)(Kt + (size_t)(b * 128 + i0 + lm) * 256 + kc * 32 + quad * 8);
    vb[kc] = *(const short8*)(Vt + (size_t)(b * 128 + j0 + wv * 16 + lm) * 256 + kc * 32 + quad * 8);
  }
  floatx4 acc = {0.f, 0.f, 0.f, 0.f};
#pragma unroll
  for (int kc = 0; kc < 8; kc++) acc = MFMA16(ka[kc], vb[kc], acc);
#pragma unroll
  for (int j = 0; j < 4; j++) {
    size_t off = sb + (size_t)(i0 + quad * 4 + j) * 128 + j0 + wv * 16 + lm;
    st_out[off] = acc[j] + state[off];
  }
  if (j0 == 0) {
    if (tid < 128) {
      int i = tid >> 3, seg = tid & 7;
      const unsigned short* kr = Kt + (size_t)(b * 128 + i0 + i) * 256 + seg * 32;
      float zs = 0.f;
#pragma unroll
      for (int x = 0; x < 4; x++) {
        short8 kv = *(const short8*)(kr + x * 8);
#pragma unroll
        for (int y = 0; y < 8; y++) zs += bf2f((unsigned short)kv[y]);
      }
      for (int d = 4; d; d >>= 1) zs += __shfl_xor(zs, d, 8);
      if (seg == 0) {
        size_t zo = sb + 16384 + i0 + i;
        st_out[zo] = zs + state[zo];
      }
    }
    if (sub == 0 && tid == 0 && l == 0)
      st_out[(size_t)b * SDn + SDn - 1] = state[(size_t)b * SDn + SDn - 1] + 256.f;
  }
}

// ---------------- FF l0 + LN + 4 projections (row-local, LDS only) ----------------
static __device__ void ffproj_unit(
    SmU& sm, int tid, int g0,
    const unsigned short* attnb, const unsigned short* skipb,
    const float* w1, const float* b1, const float* w2, const float* b2,
    const float* lnw1, const float* lnb1,
    const float* Wk1, const float* Wq1, const float* Wv1, const float* scw1,
    const float* scb1,
    unsigned short* Kb1, unsigned short* Qb1,
    unsigned short* Kt1, unsigned short* Vt1, unsigned short* skip1) {
  const int lane = tid & 63, wv = tid >> 6, lm = lane & 15, quad = lane >> 4;
  const int n0 = wv * 32 + lm, n1 = n0 + 16;
  short8 w1A[4], w1B[4], w2A[4], w2B[4];
#pragma unroll
  for (int kc = 0; kc < 4; kc++) {
    w1A[kc] = ldwfrag(w1 + (size_t)n0 * 128 + kc * 32 + quad * 8);
    w1B[kc] = ldwfrag(w1 + (size_t)n1 * 128 + kc * 32 + quad * 8);
    w2A[kc] = ldwfrag(w2 + (size_t)n0 * 128 + kc * 32 + quad * 8);
    w2B[kc] = ldwfrag(w2 + (size_t)n1 * 128 + kc * 32 + quad * 8);
  }
  float bi10 = b1[n0], bi11 = b1[n1], bi20 = b2[n0], bi21 = b2[n1];
  float sk0[4], sk1[4];
#pragma unroll
  for (int j = 0; j < 4; j++) {
    sk0[j] = bf2f(skipb[(size_t)(g0 + quad * 4 + j) * 128 + n0]);
    sk1[j] = bf2f(skipb[(size_t)(g0 + quad * 4 + j) * 128 + n1]);
  }
  { int r = tid >> 4, c = (tid & 15) * 8;
    *(short8*)&sm.f.xa[r][c] = *(const short8*)(attnb + (size_t)(g0 + r) * 128 + c); }
  __syncthreads();

  { floatx4 a0 = {0.f,0.f,0.f,0.f}, a1 = {0.f,0.f,0.f,0.f};
#pragma unroll
    for (int kc = 0; kc < 4; kc++) {
      short8 a = *(const short8*)&sm.f.xa[lm][kc * 32 + quad * 8];
      a0 = MFMA16(a, w1A[kc], a0);
      a1 = MFMA16(a, w1B[kc], a1);
    }
#pragma unroll
    for (int j = 0; j < 4; j++) {
      int row = quad * 4 + j;
      sm.f.hs[row][n0] = f2bf(fmaxf(a0[j] + bi10, 0.f));
      sm.f.hs[row][n1] = f2bf(fmaxf(a1[j] + bi11, 0.f));
    } }
  __syncthreads();
  { floatx4 a0 = {0.f,0.f,0.f,0.f}, a1 = {0.f,0.f,0.f,0.f};
#pragma unroll
    for (int kc = 0; kc < 4; kc++) {
      short8 a = *(const short8*)&sm.f.hs[lm][kc * 32 + quad * 8];
      a0 = MFMA16(a, w2A[kc], a0);
      a1 = MFMA16(a, w2B[kc], a1);
    }
#pragma unroll
    for (int j = 0; j < 4; j++) {
      int row = quad * 4 + j;
      sm.f.os[row][n0] = fmaxf(a0[j] + bi20, 0.f) + sk0[j];
      sm.f.os[row][n1] = fmaxf(a1[j] + bi21, 0.f) + sk1[j];
    } }
  __syncthreads();
  { int r = tid >> 4, c0 = (tid & 15) * 8;
    float v[8];
#pragma unroll
    for (int i = 0; i < 8; i++) v[i] = sm.f.os[r][c0 + i];
    float sm_ = 0.f, sq = 0.f;
#pragma unroll
    for (int i = 0; i < 8; i++) { sm_ += v[i]; sq += v[i] * v[i]; }
    for (int d = 8; d; d >>= 1) { sm_ += __shfl_xor(sm_, d, 16); sq += __shfl_xor(sq, d, 16); }
    float mean = sm_ * (1.f / 128.f);
    float rstd = rsqrtf(sq * (1.f / 128.f) - mean * mean + 1e-5f);
    short8 xv;
#pragma unroll
    for (int i = 0; i < 8; i++)
      xv[i] = (short)f2bf((v[i] - mean) * rstd * lnw1[c0 + i] + lnb1[c0 + i]);
    *(short8*)&sm.f.xsl[r][c0] = xv; }
  __syncthreads();
  const int bb = g0 >> 8, t0l = g0 & 255;
#pragma unroll
  for (int by = 0; by < 4; by++) {
    const float* W = by == 0 ? Wk1 : by == 1 ? Wq1 : by == 2 ? Wv1 : scw1;
    floatx4 a0 = {0.f,0.f,0.f,0.f}, a1 = {0.f,0.f,0.f,0.f};
#pragma unroll
    for (int kc = 0; kc < 4; kc++) {
      short8 a  = *(const short8*)&sm.f.xsl[lm][kc * 32 + quad * 8];
      short8 bA = ldwfrag(W + (size_t)n0 * 128 + kc * 32 + quad * 8);
      short8 bB = ldwfrag(W + (size_t)n1 * 128 + kc * 32 + quad * 8);
      a0 = MFMA16(a, bA, a0);
      a1 = MFMA16(a, bB, a1);
    }
    proj_epilogue(by, g0, bb, t0l, n0, n1, quad, a0, a1,
                  Kb1, Kt1, Qb1, Vt1, skip1, scb1);
  }
}

static __device__ void ffu_unit(
    SmU& sm, int tid, int g0,
    const unsigned short* attnb, const unsigned short* skipb,
    const float* w1, const float* b1, const float* w2, const float* b2,
    const float* unw, const float* unb, float* yout) {
  const int lane = tid & 63, wv = tid >> 6, lm = lane & 15, quad = lane >> 4;
  const int n0 = wv * 32 + lm, n1 = n0 + 16;
  short8 w1A[4], w1B[4], w2A[4], w2B[4], uA[4], uB[4];
#pragma unroll
  for (int kc = 0; kc < 4; kc++) {
    w1A[kc] = ldwfrag(w1 + (size_t)n0 * 128 + kc * 32 + quad * 8);
    w1B[kc] = ldwfrag(w1 + (size_t)n1 * 128 + kc * 32 + quad * 8);
    w2A[kc] = ldwfrag(w2 + (size_t)n0 * 128 + kc * 32 + quad * 8);
    w2B[kc] = ldwfrag(w2 + (size_t)n1 * 128 + kc * 32 + quad * 8);
    uA[kc]  = ldwfrag(unw + (size_t)n0 * 128 + kc * 32 + quad * 8);
    uB[kc]  = ldwfrag(unw + (size_t)n1 * 128 + kc * 32 + quad * 8);
  }
  float bi10 = b1[n0], bi11 = b1[n1], bi20 = b2[n0], bi21 = b2[n1];
  float u0b = unb[n0], u1b = unb[n1];
  float sk0[4], sk1[4];
#pragma unroll
  for (int j = 0; j < 4; j++) {
    sk0[j] = bf2f(skipb[(size_t)(g0 + quad * 4 + j) * 128 + n0]);
    sk1[j] = bf2f(skipb[(size_t)(g0 + quad * 4 + j) * 128 + n1]);
  }
  { int r = tid >> 4, c = (tid & 15) * 8;
    *(short8*)&sm.f.xa[r][c] = *(const short8*)(attnb + (size_t)(g0 + r) * 128 + c); }
  __syncthreads();

  { floatx4 a0 = {0.f,0.f,0.f,0.f}, a1 = {0.f,0.f,0.f,0.f};
#pragma unroll
    for (int kc = 0; kc < 4; kc++) {
      short8 a = *(const short8*)&sm.f.xa[lm][kc * 32 + quad * 8];
      a0 = MFMA16(a, w1A[kc], a0);
      a1 = MFMA16(a, w1B[kc], a1);
    }
#pragma unroll
    for (int j = 0; j < 4; j++) {
      int row = quad * 4 + j;
      sm.f.hs[row][n0] = f2bf(fmaxf(a0[j] + bi10, 0.f));
      sm.f.hs[row][n1] = f2bf(fmaxf(a1[j] + bi11, 0.f));
    } }
  __syncthreads();
  float o0[4], o1[4];
  { floatx4 a0 = {0.f,0.f,0.f,0.f}, a1 = {0.f,0.f,0.f,0.f};
#pragma unroll
    for (int kc = 0; kc < 4; kc++) {
      short8 a = *(const short8*)&sm.f.hs[lm][kc * 32 + quad * 8];
      a0 = MFMA16(a, w2A[kc], a0);
      a1 = MFMA16(a, w2B[kc], a1);
    }
#pragma unroll
    for (int j = 0; j < 4; j++) {
      o0[j] = fmaxf(a0[j] + bi20, 0.f) + sk0[j];
      o1[j] = fmaxf(a1[j] + bi21, 0.f) + sk1[j];
    } }
  __syncthreads();
#pragma unroll
  for (int j = 0; j < 4; j++) {
    int row = quad * 4 + j;
    sm.f.hs[row][n0] = f2bf(o0[j]);
    sm.f.hs[row][n1] = f2bf(o1[j]);
  }
  __syncthreads();
  { floatx4 a0 = {0.f,0.f,0.f,0.f}, a1 = {0.f,0.f,0.f,0.f};
#pragma unroll
    for (int kc = 0; kc < 4; kc++) {
      short8 a = *(const short8*)&sm.f.hs[lm][kc * 32 + quad * 8];
      a0 = MFMA16(a, uA[kc], a0);
      a1 = MFMA16(a, uB[kc], a1);
    }
#pragma unroll
    for (int j = 0; j < 4; j++) {
      int gg = g0 + quad * 4 + j;
      int bb = gg >> 8, tq = gg & 255;
      yout[(size_t)(tq * Bn + bb) * 128 + n0] = a0[j] + u0b;
      yout[(size_t)(tq * Bn + bb) * 128 + n1] = a1[j] + u1b;
    } }
}

// ---------------- the persistent kernel: 5 stages, 4 barriers ----------------
__global__ __launch_bounds__(256, 1) void persistent_kernel(
    const float* z, const float* state,
    const float* Wk, const float* Wq, const float* Wv,
    const float* lnw, const float* lnb,
    const float* w1, const float* b1, const float* w2, const float* b2,
    const float* scw, const float* scb,
    const float* unw, const float* unb,
    float* yout, float* st_out,
    unsigned short* Kb0, unsigned short* Qb0, unsigned short* Kt0, unsigned short* Vt0,
    unsigned short* Kb1, unsigned short* Qb1, unsigned short* Kt1, unsigned short* Vt1,
    unsigned short* skip0, unsigned short* skip1, unsigned short* attnb,
    unsigned short* S0t, unsigned* bar) {
  __shared__ SmU sm;
  const int tid = threadIdx.x, bx = blockIdx.x;

  // ---- S0: rotate+LN+proj l0 (+S0t on blocks 0..15)
  proj0_pair(sm, tid, bx, z, state, Wk, Wq, Wv, scw,
             lnw, lnb, scb, Kb0, Qb0, Kt0, Vt0, skip0);
  if (bx < 16) s0t_unit(sm, tid, bx, state, S0t);
  gridbar(bar + 0);

  // ---- S1: attn l0
  attn_unit(sm, tid, bx, 0, Kb0, Qb0, Vt0, S0t, state, attnb);
  gridbar(bar + 16);

  // ---- S2: ff l0 + LN + proj l1 | state l0
  if (bx < 128)
    ffproj_unit(sm, tid, bx * 16, attnb, skip0, w1, b1, w2, b2,
                lnw + 128, lnb + 128,
                Wk + 16384, Wq + 16384, Wv + 16384, scw + 16384, scb + 128,
                Kb1, Qb1, Kt1, Vt1, skip1);
  else
    state_unit(tid, bx - 128, 0, Kt0, Vt0, state, st_out);
  gridbar(bar + 32);

  // ---- S3: attn l1
  attn_unit(sm, tid, bx, 1, Kb1, Qb1, Vt1, S0t + (size_t)8 * 16384, state, attnb);
  gridbar(bar + 48);

  // ---- S4: ffu | state l1
  if (bx < 128)
    ffu_unit(sm, tid, bx * 16, attnb, skip1,
             w1 + 16384, b1 + 128, w2 + 16384, b2 + 128, unw, unb, yout);
  else
    state_unit(tid, bx - 128, 1, Kt1, Vt1, state, st_out);
}

// ============================================================ launch
extern "C" void kernel_launch(void* const* d_in, const int* in_sizes, int n_in,
                              void* d_out, int out_size, void* d_ws, size_t ws_size,
                              hipStream_t stream) {
  const float* z       = (const float*)d_in[0];
  const float* state   = (const float*)d_in[1];
  const float* Wk      = (const float*)d_in[2];
  const float* Wq      = (const float*)d_in[3];
  const float* Wv      = (const float*)d_in[4];
  const float* ln_w    = (const float*)d_in[5];
  const float* ln_b    = (const float*)d_in[6];
  const float* ff_w1   = (const float*)d_in[7];
  const float* ff_b1   = (const float*)d_in[8];
  const float* ff_w2   = (const float*)d_in[9];
  const float* ff_b2   = (const float*)d_in[10];
  const float* sc_w    = (const float*)d_in[11];
  const float* sc_b    = (const float*)d_in[12];
  const float* unmap_w = (const float*)d_in[13];
  const float* unmap_b = (const float*)d_in[14];

  float* y_out  = (float*)d_out;                      // (T,B,128)
  float* st_out = y_out + (size_t)Tn * Bn * 128;      // (B,SDn)

  const size_t E = 262144;                            // 2048*128
  unsigned short* Kb0   = (unsigned short*)d_ws;
  unsigned short* Qb0   = Kb0 + E;
  unsigned short* Kt0   = Qb0 + E;
  unsigned short* Vt0   = Kt0 + E;
  unsigned short* Kb1   = Vt0 + E;
  unsigned short* Qb1   = Kb1 + E;
  unsigned short* Kt1   = Qb1 + E;
  unsigned short* Vt1   = Kt1 + E;
  unsigned short* skip0 = Vt1 + E;
  unsigned short* skip1 = skip0 + E;
  unsigned short* attnb = skip1 + E;
  unsigned short* S0t   = attnb + E;                  // 2*8*16384 bf16
  unsigned* bar = (unsigned*)(S0t + (size_t)2 * 8 * 16384);

  hipMemsetAsync(bar, 0, 512, stream);                // zero barrier counters

  persistent_kernel<<<NBLK, 256, 0, stream>>>(
      z, state, Wk, Wq, Wv, ln_w, ln_b,
      ff_w1, ff_b1, ff_w2, ff_b2, sc_w, sc_b, unmap_w, unmap_b,
      y_out, st_out,
      Kb0, Qb0, Kt0, Vt0, Kb1, Qb1, Kt1, Vt1,
      skip0, skip1, attnb, S0t, bar);
}

// Round 10
// 131.201 us; speedup vs baseline: 2.1216x; 1.5550x over previous
//
#include <hip/hip_runtime.h>
#include <math.h>

#define Bn 8
#define Tn 256
#define COREn 16512
#define SDn   33025

typedef __attribute__((ext_vector_type(8))) short short8;
typedef __attribute__((ext_vector_type(4))) short short4v;
typedef __attribute__((ext_vector_type(4))) float floatx4;

#define MFMA16(a,b,c) __builtin_amdgcn_mfma_f32_16x16x32_bf16(a,b,c,0,0,0)

static __device__ __forceinline__ unsigned short f2bf(float f) {
  unsigned int u = __float_as_uint(f);
  return (unsigned short)((u + 0x7FFFu + ((u >> 16) & 1u)) >> 16);
}
static __device__ __forceinline__ float bf2f(unsigned short h) {
  return __uint_as_float((unsigned int)h << 16);
}
static __device__ __forceinline__ short8 ldwfrag(const float* p) {
  float4 a = *(const float4*)p;
  float4 b = *(const float4*)(p + 4);
  short8 r;
  r[0] = (short)f2bf(a.x); r[1] = (short)f2bf(a.y);
  r[2] = (short)f2bf(a.z); r[3] = (short)f2bf(a.w);
  r[4] = (short)f2bf(b.x); r[5] = (short)f2bf(b.y);
  r[6] = (short)f2bf(b.z); r[7] = (short)f2bf(b.w);
  return r;
}
static __device__ __forceinline__ void ld8(const float* p, float* v) {
  float4 a = *(const float4*)p, b = *(const float4*)(p + 4);
  v[0]=a.x; v[1]=a.y; v[2]=a.z; v[3]=a.w; v[4]=b.x; v[5]=b.y; v[6]=b.z; v[7]=b.w;
}

// --------------------------------------------------------- proj epilogue
// by: 0=K(elu+1, Kb+Kt) 1=Q(elu+1) 2=V(Vt) 3=skip(+scb, bf16)
static __device__ __forceinline__ void proj_epilogue(
    int by, int g0, int b, int t0l, int n0, int n1, int quad,
    floatx4 acc0, floatx4 acc1,
    unsigned short* __restrict__ Kb, unsigned short* __restrict__ Kt,
    unsigned short* __restrict__ Qb, unsigned short* __restrict__ Vt,
    unsigned short* __restrict__ skipb, const float* __restrict__ scb) {
  if (by == 0) {
    short4v kt0, kt1;
#pragma unroll
    for (int j = 0; j < 4; j++) {
      int row = quad * 4 + j;
      float e0 = acc0[j] > 0.f ? acc0[j] + 1.f : expf(acc0[j]);
      float e1 = acc1[j] > 0.f ? acc1[j] + 1.f : expf(acc1[j]);
      Kb[(size_t)(g0 + row) * 128 + n0] = f2bf(e0);
      Kb[(size_t)(g0 + row) * 128 + n1] = f2bf(e1);
      kt0[j] = (short)f2bf(e0); kt1[j] = (short)f2bf(e1);
    }
    *(short4v*)(Kt + (size_t)(b * 128 + n0) * 256 + t0l + quad * 4) = kt0;
    *(short4v*)(Kt + (size_t)(b * 128 + n1) * 256 + t0l + quad * 4) = kt1;
  } else if (by == 1) {
#pragma unroll
    for (int j = 0; j < 4; j++) {
      int row = quad * 4 + j;
      float e0 = acc0[j] > 0.f ? acc0[j] + 1.f : expf(acc0[j]);
      float e1 = acc1[j] > 0.f ? acc1[j] + 1.f : expf(acc1[j]);
      Qb[(size_t)(g0 + row) * 128 + n0] = f2bf(e0);
      Qb[(size_t)(g0 + row) * 128 + n1] = f2bf(e1);
    }
  } else if (by == 2) {
    short4v v0, v1;
#pragma unroll
    for (int j = 0; j < 4; j++) { v0[j] = (short)f2bf(acc0[j]); v1[j] = (short)f2bf(acc1[j]); }
    *(short4v*)(Vt + (size_t)(b * 128 + n0) * 256 + t0l + quad * 4) = v0;
    *(short4v*)(Vt + (size_t)(b * 128 + n1) * 256 + t0l + quad * 4) = v1;
  } else {
    float sb0 = scb[n0], sb1 = scb[n1];
#pragma unroll
    for (int j = 0; j < 4; j++) {
      int row = quad * 4 + j;
      skipb[(size_t)(g0 + row) * 128 + n0] = f2bf(acc0[j] + sb0);
      skipb[(size_t)(g0 + row) * 128 + n1] = f2bf(acc1[j] + sb1);
    }
  }
}

// =========================================================== prep: proj l0 (512) + S0t (16)
__global__ __launch_bounds__(256) void prep_kernel(
    const float* __restrict__ z, const float* __restrict__ state,
    const float* __restrict__ Wk, const float* __restrict__ Wq,
    const float* __restrict__ Wv, const float* __restrict__ scw,
    const float* __restrict__ lnw, const float* __restrict__ lnb,
    const float* __restrict__ scb,
    unsigned short* __restrict__ Kb0, unsigned short* __restrict__ Qb0,
    unsigned short* __restrict__ Kt0, unsigned short* __restrict__ Vt0,
    unsigned short* __restrict__ skip0, unsigned short* __restrict__ S0t) {
  const int tid = threadIdx.x, bx = blockIdx.x;
  if (bx < 512) {
    __shared__ unsigned short xs[16][136];
    const int lane = tid & 63, wv = tid >> 6, lm = lane & 15, quad = lane >> 4;
    const int tile = bx >> 2, by = bx & 3;
    const int g0 = tile * 16;
    const int r = tid >> 4, c0 = (tid & 15) * 8;
    const int g = g0 + r, b = g >> 8, t = g & 255;
    float v[8], pv[8];
    const float* zr = z + ((size_t)t * Bn + b) * 128;
    ld8(zr + c0, v);
    ld8(zr + (c0 ^ 64), pv);
    float pos = state[(size_t)b * SDn + SDn - 1] + (float)t;
#pragma unroll
    for (int i = 0; i < 8; i++) {
      int jj = (c0 + i) & 63;
      float ang = pos * expf((float)jj * -0.14391156831212787f);
      float sn = sinf(ang), cs = cosf(ang);
      v[i] = (c0 < 64) ? (v[i] * cs - pv[i] * sn) : (v[i] * cs + pv[i] * sn);
    }
    float sm = 0.f, sq = 0.f;
#pragma unroll
    for (int i = 0; i < 8; i++) { sm += v[i]; sq += v[i] * v[i]; }
    for (int d = 8; d; d >>= 1) { sm += __shfl_xor(sm, d, 16); sq += __shfl_xor(sq, d, 16); }
    float mean = sm * (1.f / 128.f);
    float rstd = rsqrtf(sq * (1.f / 128.f) - mean * mean + 1e-5f);
    short8 xv;
#pragma unroll
    for (int i = 0; i < 8; i++)
      xv[i] = (short)f2bf((v[i] - mean) * rstd * lnw[c0 + i] + lnb[c0 + i]);
    *(short8*)&xs[r][c0] = xv;
    __syncthreads();

    const float* W = by == 0 ? Wk : by == 1 ? Wq : by == 2 ? Wv : scw;
    const int bb = g0 >> 8, t0l = g0 & 255;
    const int n0 = wv * 32 + lm, n1 = n0 + 16;
    floatx4 a0 = {0.f,0.f,0.f,0.f}, a1 = {0.f,0.f,0.f,0.f};
#pragma unroll
    for (int kc = 0; kc < 4; kc++) {
      short8 a  = *(const short8*)&xs[lm][kc * 32 + quad * 8];
      short8 bA = ldwfrag(W + (size_t)n0 * 128 + kc * 32 + quad * 8);
      short8 bB = ldwfrag(W + (size_t)n1 * 128 + kc * 32 + quad * 8);
      a0 = MFMA16(a, bA, a0);
      a1 = MFMA16(a, bB, a1);
    }
    proj_epilogue(by, g0, bb, t0l, n0, n1, quad, a0, a1,
                  Kb0, Kt0, Qb0, Vt0, skip0, scb);
  } else {
    // ------- S0 -> S0t (bf16, transposed), both layers -------
    __shared__ float tl[32][33];
    const int id = bx - 512, b = id >> 1, l = id & 1;
    const float* src = state + (size_t)b * SDn + (size_t)l * COREn;
    unsigned short* dst = S0t + (size_t)(l * 8 + b) * 16384;
    const int r = tid >> 3, c4 = (tid & 7) * 4;
#pragma unroll
    for (int tI = 0; tI < 4; tI++)
      for (int tJ = 0; tJ < 4; tJ++) {
        int i0 = tI * 32, j0 = tJ * 32;
#pragma unroll
        for (int q = 0; q < 4; q++)
          tl[r][c4 + q] = src[(size_t)(i0 + r) * 128 + j0 + c4 + q];
        __syncthreads();
        short4v o;
#pragma unroll
        for (int q = 0; q < 4; q++) o[q] = (short)f2bf(tl[c4 + q][r]);
        *(short4v*)(dst + (size_t)(j0 + r) * 128 + i0 + c4) = o;
        __syncthreads();
      }
  }
}

// =========================================================== state update (device fn)
static __device__ void state_upd(
    int tid, int idx, int l,
    const unsigned short* __restrict__ Kt, const unsigned short* __restrict__ Vt,
    const float* __restrict__ state, float* __restrict__ st_out) {
  const int lane = tid & 63, wv = tid >> 6, lm = lane & 15, quad = lane >> 4;
  const int b = idx >> 4, sub = idx & 15;
  const int i0 = (sub >> 1) * 16, j0 = (sub & 1) * 64;
  const size_t sb = (size_t)b * SDn + (size_t)l * COREn;
  floatx4 acc = {0.f, 0.f, 0.f, 0.f};
#pragma unroll
  for (int kc = 0; kc < 8; kc++) {
    short8 ka = *(const short8*)(Kt + (size_t)(b * 128 + i0 + lm) * 256 + kc * 32 + quad * 8);
    short8 vb = *(const short8*)(Vt + (size_t)(b * 128 + j0 + wv * 16 + lm) * 256 + kc * 32 + quad * 8);
    acc = MFMA16(ka, vb, acc);
  }
#pragma unroll
  for (int j = 0; j < 4; j++) {
    size_t off = sb + (size_t)(i0 + quad * 4 + j) * 128 + j0 + wv * 16 + lm;
    st_out[off] = acc[j] + state[off];
  }
  if (j0 == 0) {
    if (tid < 128) {
      int i = tid >> 3, seg = tid & 7;
      const unsigned short* kr = Kt + (size_t)(b * 128 + i0 + i) * 256 + seg * 32;
      float zs = 0.f;
#pragma unroll
      for (int x = 0; x < 4; x++) {
        short8 kv = *(const short8*)(kr + x * 8);
#pragma unroll
        for (int y = 0; y < 8; y++) zs += bf2f((unsigned short)kv[y]);
      }
      for (int d = 4; d; d >>= 1) zs += __shfl_xor(zs, d, 8);
      if (seg == 0) {
        size_t zo = sb + 16384 + i0 + i;
        st_out[zo] = zs + state[zo];
      }
    }
    if (sub == 0 && tid == 0 && l == 0)
      st_out[(size_t)b * SDn + SDn - 1] = state[(size_t)b * SDn + SDn - 1] + 256.f;
  }
}

// =========================================================== attention (256 col-split) + state (128)
__global__ __launch_bounds__(256) void attn_kernel(
    const unsigned short* __restrict__ Kb, const unsigned short* __restrict__ Qb,
    const unsigned short* __restrict__ Vt, const unsigned short* __restrict__ Kt,
    const unsigned short* __restrict__ S0tl, const float* __restrict__ state,
    unsigned short* __restrict__ attnb, float* __restrict__ st_out, int l) {
  const int tid = threadIdx.x, bx = blockIdx.x;
  const int lane = tid & 63, wv = tid >> 6, lm = lane & 15, quad = lane >> 4;
  if (bx < 256) {
    __shared__ unsigned short xs[16][136];
    __shared__ unsigned short Ssc[4][16][40];
    __shared__ float Obuf[4][16][68];
    __shared__ float Z0s[128];
    __shared__ float denw[4][16];
    __shared__ float denz[16];
    __shared__ float dinv[16];

    const int tile = bx >> 1, half = bx & 1;
    const int b = tile >> 4, rt = tile & 15, t0 = rt * 16;
    const size_t sb = (size_t)b * SDn + (size_t)l * COREn;
    { int r = tid >> 4, c = (tid & 15) * 8;
      *(short8*)&xs[r][c] = *(const short8*)(Qb + (size_t)(b * 256 + t0 + r) * 128 + c); }
    if (tid < 128) Z0s[tid] = state[sb + 16384 + tid];
    __syncthreads();

    { int r = tid >> 4, c = (tid & 15) * 8;
      float qz = 0.f;
#pragma unroll
      for (int i = 0; i < 8; i++) qz += bf2f(xs[r][c + i]) * Z0s[c + i];
      for (int d = 8; d; d >>= 1) qz += __shfl_xor(qz, d, 16);
      if ((tid & 15) == 0) denz[r] = qz; }

    floatx4 oacc[4];
#pragma unroll
    for (int jt = 0; jt < 4; jt++) oacc[jt] = floatx4{0.f, 0.f, 0.f, 0.f};
    float dacc[4] = {0.f, 0.f, 0.f, 0.f};

    const int nch = rt / 2 + 1;
    for (int c = wv; c < nch; c += 4) {
      const int kb = c * 32;
      short8 vfr[4];
#pragma unroll
      for (int jt = 0; jt < 4; jt++)
        vfr[jt] = *(const short8*)(Vt + (size_t)(b * 128 + half * 64 + jt * 16 + lm) * 256 + kb + quad * 8);
      floatx4 s0 = {0.f,0.f,0.f,0.f}, s1 = {0.f,0.f,0.f,0.f};
#pragma unroll
      for (int kc = 0; kc < 4; kc++) {
        short8 a  = *(const short8*)&xs[lm][kc * 32 + quad * 8];
        short8 k0 = *(const short8*)(Kb + (size_t)(b * 256 + kb + lm) * 128 + kc * 32 + quad * 8);
        short8 k1 = *(const short8*)(Kb + (size_t)(b * 256 + kb + 16 + lm) * 128 + kc * 32 + quad * 8);
        s0 = MFMA16(a, k0, s0);
        s1 = MFMA16(a, k1, s1);
      }
      const int tau0 = kb + lm, tau1 = kb + 16 + lm;
#pragma unroll
      for (int j = 0; j < 4; j++) {
        int m = t0 + quad * 4 + j;
        float v0 = (tau0 <= m) ? s0[j] : 0.f;
        float v1 = (tau1 <= m) ? s1[j] : 0.f;
        dacc[j] += v0 + v1;
        Ssc[wv][quad * 4 + j][lm]      = f2bf(v0);
        Ssc[wv][quad * 4 + j][16 + lm] = f2bf(v1);
      }
      short8 sa = *(const short8*)&Ssc[wv][lm][quad * 8];
#pragma unroll
      for (int jt = 0; jt < 4; jt++)
        oacc[jt] = MFMA16(sa, vfr[jt], oacc[jt]);
    }

    // Q @ S0 via pre-transposed bf16 S0t
    { short8 aq = *(const short8*)&xs[lm][wv * 32 + quad * 8];
#pragma unroll
      for (int jt = 0; jt < 4; jt++) {
        short8 vb = *(const short8*)(S0tl + (size_t)b * 16384 +
                        (size_t)(half * 64 + jt * 16 + lm) * 128 + wv * 32 + quad * 8);
        oacc[jt] = MFMA16(aq, vb, oacc[jt]);
      } }

#pragma unroll
    for (int j = 0; j < 4; j++)
      for (int d = 8; d; d >>= 1) dacc[j] += __shfl_xor(dacc[j], d, 16);
    if (lm == 0) {
#pragma unroll
      for (int j = 0; j < 4; j++) denw[wv][quad * 4 + j] = dacc[j];
    }
#pragma unroll
    for (int jt = 0; jt < 4; jt++)
#pragma unroll
      for (int j = 0; j < 4; j++)
        Obuf[wv][quad * 4 + j][jt * 16 + lm] = oacc[jt][j];
    __syncthreads();
    if (tid < 16)
      dinv[tid] = 1.f / (denz[tid] + denw[0][tid] + denw[1][tid]
                         + denw[2][tid] + denw[3][tid] + 1e-5f);
    __syncthreads();
    { int r = tid >> 4, c = (tid & 15) * 4;
      float di = dinv[r];
      short4v ov;
#pragma unroll
      for (int q = 0; q < 4; q++) {
        float o = Obuf[0][r][c + q] + Obuf[1][r][c + q]
                + Obuf[2][r][c + q] + Obuf[3][r][c + q];
        ov[q] = (short)f2bf(o * di);
      }
      *(short4v*)(attnb + (size_t)(b * 256 + t0 + r) * 128 + half * 64 + c) = ov; }
  } else {
    state_upd(tid, bx - 256, l, Kt, Vt, state, st_out);
  }
}

// =========================================================== FF + LN -> xln1  (128 blocks)
__global__ __launch_bounds__(256) void ffln_kernel(
    const unsigned short* __restrict__ attnb, const unsigned short* __restrict__ skipb,
    const float* __restrict__ w1, const float* __restrict__ b1,
    const float* __restrict__ w2, const float* __restrict__ b2,
    const float* __restrict__ lnw1, const float* __restrict__ lnb1,
    unsigned short* __restrict__ xln1) {
  __shared__ unsigned short xa[16][136];
  __shared__ unsigned short hs[16][136];
  __shared__ float os[16][132];
  const int tid = threadIdx.x, g0 = blockIdx.x * 16;
  const int lane = tid & 63, wv = tid >> 6, lm = lane & 15, quad = lane >> 4;
  const int n0 = wv * 32 + lm, n1 = n0 + 16;

  // early independent loads: weight frags, biases, skip
  short8 w1A[4], w1B[4], w2A[4], w2B[4];
#pragma unroll
  for (int kc = 0; kc < 4; kc++) {
    w1A[kc] = ldwfrag(w1 + (size_t)n0 * 128 + kc * 32 + quad * 8);
    w1B[kc] = ldwfrag(w1 + (size_t)n1 * 128 + kc * 32 + quad * 8);
    w2A[kc] = ldwfrag(w2 + (size_t)n0 * 128 + kc * 32 + quad * 8);
    w2B[kc] = ldwfrag(w2 + (size_t)n1 * 128 + kc * 32 + quad * 8);
  }
  float bi10 = b1[n0], bi11 = b1[n1], bi20 = b2[n0], bi21 = b2[n1];
  float sk0[4], sk1[4];
#pragma unroll
  for (int j = 0; j < 4; j++) {
    sk0[j] = bf2f(skipb[(size_t)(g0 + quad * 4 + j) * 128 + n0]);
    sk1[j] = bf2f(skipb[(size_t)(g0 + quad * 4 + j) * 128 + n1]);
  }
  { int r = tid >> 4, c = (tid & 15) * 8;
    *(short8*)&xa[r][c] = *(const short8*)(attnb + (size_t)(g0 + r) * 128 + c); }
  __syncthreads();

  { floatx4 a0 = {0.f,0.f,0.f,0.f}, a1 = {0.f,0.f,0.f,0.f};
#pragma unroll
    for (int kc = 0; kc < 4; kc++) {
      short8 a = *(const short8*)&xa[lm][kc * 32 + quad * 8];
      a0 = MFMA16(a, w1A[kc], a0);
      a1 = MFMA16(a, w1B[kc], a1);
    }
#pragma unroll
    for (int j = 0; j < 4; j++) {
      int row = quad * 4 + j;
      hs[row][n0] = f2bf(fmaxf(a0[j] + bi10, 0.f));
      hs[row][n1] = f2bf(fmaxf(a1[j] + bi11, 0.f));
    } }
  __syncthreads();
  { floatx4 a0 = {0.f,0.f,0.f,0.f}, a1 = {0.f,0.f,0.f,0.f};
#pragma unroll
    for (int kc = 0; kc < 4; kc++) {
      short8 a = *(const short8*)&hs[lm][kc * 32 + quad * 8];
      a0 = MFMA16(a, w2A[kc], a0);
      a1 = MFMA16(a, w2B[kc], a1);
    }
#pragma unroll
    for (int j = 0; j < 4; j++) {
      int row = quad * 4 + j;
      os[row][n0] = fmaxf(a0[j] + bi20, 0.f) + sk0[j];
      os[row][n1] = fmaxf(a1[j] + bi21, 0.f) + sk1[j];
    } }
  __syncthreads();
  { int r = tid >> 4, c0 = (tid & 15) * 8;
    float v[8];
#pragma unroll
    for (int i = 0; i < 8; i++) v[i] = os[r][c0 + i];
    float sm = 0.f, sq = 0.f;
#pragma unroll
    for (int i = 0; i < 8; i++) { sm += v[i]; sq += v[i] * v[i]; }
    for (int d = 8; d; d >>= 1) { sm += __shfl_xor(sm, d, 16); sq += __shfl_xor(sq, d, 16); }
    float mean = sm * (1.f / 128.f);
    float rstd = rsqrtf(sq * (1.f / 128.f) - mean * mean + 1e-5f);
    short8 xv;
#pragma unroll
    for (int i = 0; i < 8; i++)
      xv[i] = (short)f2bf((v[i] - mean) * rstd * lnw1[c0 + i] + lnb1[c0 + i]);
    *(short8*)(xln1 + (size_t)(g0 + r) * 128 + c0) = xv; }
}

// =========================================================== proj l1 (512 blocks)
__global__ __launch_bounds__(256) void proj1_kernel(
    const unsigned short* __restrict__ xln1,
    const float* __restrict__ Wk, const float* __restrict__ Wq,
    const float* __restrict__ Wv, const float* __restrict__ scw,
    const float* __restrict__ scb,
    unsigned short* __restrict__ Kb1, unsigned short* __restrict__ Qb1,
    unsigned short* __restrict__ Kt1, unsigned short* __restrict__ Vt1,
    unsigned short* __restrict__ skip1) {
  __shared__ unsigned short xs[16][136];
  const int tid = threadIdx.x, bx = blockIdx.x;
  const int lane = tid & 63, wv = tid >> 6, lm = lane & 15, quad = lane >> 4;
  const int tile = bx >> 2, by = bx & 3;
  const int g0 = tile * 16;
  { int r = tid >> 4, c = (tid & 15) * 8;
    *(short8*)&xs[r][c] = *(const short8*)(xln1 + (size_t)(g0 + r) * 128 + c); }
  __syncthreads();
  const float* W = by == 0 ? Wk : by == 1 ? Wq : by == 2 ? Wv : scw;
  const int bb = g0 >> 8, t0l = g0 & 255;
  const int n0 = wv * 32 + lm, n1 = n0 + 16;
  floatx4 a0 = {0.f,0.f,0.f,0.f}, a1 = {0.f,0.f,0.f,0.f};
#pragma unroll
  for (int kc = 0; kc < 4; kc++) {
    short8 a  = *(const short8*)&xs[lm][kc * 32 + quad * 8];
    short8 bA = ldwfrag(W + (size_t)n0 * 128 + kc * 32 + quad * 8);
    short8 bB = ldwfrag(W + (size_t)n1 * 128 + kc * 32 + quad * 8);
    a0 = MFMA16(a, bA, a0);
    a1 = MFMA16(a, bB, a1);
  }
  proj_epilogue(by, g0, bb, t0l, n0, n1, quad, a0, a1,
                Kb1, Kt1, Qb1, Vt1, skip1, scb);
}

// =========================================================== FF + unmap -> y (128 blocks)
__global__ __launch_bounds__(256) void ffu_kernel(
    const unsigned short* __restrict__ attnb, const unsigned short* __restrict__ skipb,
    const float* __restrict__ w1, const float* __restrict__ b1,
    const float* __restrict__ w2, const float* __restrict__ b2,
    const float* __restrict__ unw, const float* __restrict__ unb,
    float* __restrict__ yout) {
  __shared__ unsigned short xa[16][136];
  __shared__ unsigned short hs[16][136];
  const int tid = threadIdx.x, g0 = blockIdx.x * 16;
  const int lane = tid & 63, wv = tid >> 6, lm = lane & 15, quad = lane >> 4;
  const int n0 = wv * 32 + lm, n1 = n0 + 16;

  short8 w1A[4], w1B[4], w2A[4], w2B[4];
#pragma unroll
  for (int kc = 0; kc < 4; kc++) {
    w1A[kc] = ldwfrag(w1 + (size_t)n0 * 128 + kc * 32 + quad * 8);
    w1B[kc] = ldwfrag(w1 + (size_t)n1 * 128 + kc * 32 + quad * 8);
    w2A[kc] = ldwfrag(w2 + (size_t)n0 * 128 + kc * 32 + quad * 8);
    w2B[kc] = ldwfrag(w2 + (size_t)n1 * 128 + kc * 32 + quad * 8);
  }
  float bi10 = b1[n0], bi11 = b1[n1], bi20 = b2[n0], bi21 = b2[n1];
  float sk0[4], sk1[4];
#pragma unroll
  for (int j = 0; j < 4; j++) {
    sk0[j] = bf2f(skipb[(size_t)(g0 + quad * 4 + j) * 128 + n0]);
    sk1[j] = bf2f(skipb[(size_t)(g0 + quad * 4 + j) * 128 + n1]);
  }
  { int r = tid >> 4, c = (tid & 15) * 8;
    *(short8*)&xa[r][c] = *(const short8*)(attnb + (size_t)(g0 + r) * 128 + c); }
  __syncthreads();

  { floatx4 a0 = {0.f,0.f,0.f,0.f}, a1 = {0.f,0.f,0.f,0.f};
#pragma unroll
    for (int kc = 0; kc < 4; kc++) {
      short8 a = *(const short8*)&xa[lm][kc * 32 + quad * 8];
      a0 = MFMA16(a, w1A[kc], a0);
      a1 = MFMA16(a, w1B[kc], a1);
    }
#pragma unroll
    for (int j = 0; j < 4; j++) {
      int row = quad * 4 + j;
      hs[row][n0] = f2bf(fmaxf(a0[j] + bi10, 0.f));
      hs[row][n1] = f2bf(fmaxf(a1[j] + bi11, 0.f));
    } }
  __syncthreads();
  // unmap weight frags (issue while FF2 runs)
  short8 uA[4], uB[4];
#pragma unroll
  for (int kc = 0; kc < 4; kc++) {
    uA[kc] = ldwfrag(unw + (size_t)n0 * 128 + kc * 32 + quad * 8);
    uB[kc] = ldwfrag(unw + (size_t)n1 * 128 + kc * 32 + quad * 8);
  }
  float o0[4], o1[4];
  { floatx4 a0 = {0.f,0.f,0.f,0.f}, a1 = {0.f,0.f,0.f,0.f};
#pragma unroll
    for (int kc = 0; kc < 4; kc++) {
      short8 a = *(const short8*)&hs[lm][kc * 32 + quad * 8];
      a0 = MFMA16(a, w2A[kc], a0);
      a1 = MFMA16(a, w2B[kc], a1);
    }
#pragma unroll
    for (int j = 0; j < 4; j++) {
      o0[j] = fmaxf(a0[j] + bi20, 0.f) + sk0[j];
      o1[j] = fmaxf(a1[j] + bi21, 0.f) + sk1[j];
    } }
  __syncthreads();          // all FF2 hs-reads done
#pragma unroll
  for (int j = 0; j < 4; j++) {
    int row = quad * 4 + j;
    hs[row][n0] = f2bf(o0[j]);
    hs[row][n1] = f2bf(o1[j]);
  }
  __syncthreads();
  { floatx4 a0 = {0.f,0.f,0.f,0.f}, a1 = {0.f,0.f,0.f,0.f};
#pragma unroll
    for (int kc = 0; kc < 4; kc++) {
      short8 a = *(const short8*)&hs[lm][kc * 32 + quad * 8];
      a0 = MFMA16(a, uA[kc], a0);
      a1 = MFMA16(a, uB[kc], a1);
    }
    float u0 = unb[n0], u1 = unb[n1];
#pragma unroll
    for (int j = 0; j < 4; j++) {
      int gg = g0 + quad * 4 + j;
      int bb = gg >> 8, tq = gg & 255;
      yout[(size_t)(tq * Bn + bb) * 128 + n0] = a0[j] + u0;
      yout[(size_t)(tq * Bn + bb) * 128 + n1] = a1[j] + u1;
    } }
}

// ============================================================ launch
extern "C" void kernel_launch(void* const* d_in, const int* in_sizes, int n_in,
                              void* d_out, int out_size, void* d_ws, size_t ws_size,
                              hipStream_t stream) {
  const float* z       = (const float*)d_in[0];
  const float* state   = (const float*)d_in[1];
  const float* Wk      = (const float*)d_in[2];
  const float* Wq      = (const float*)d_in[3];
  const float* Wv      = (const float*)d_in[4];
  const float* ln_w    = (const float*)d_in[5];
  const float* ln_b    = (const float*)d_in[6];
  const float* ff_w1   = (const float*)d_in[7];
  const float* ff_b1   = (const float*)d_in[8];
  const float* ff_w2   = (const float*)d_in[9];
  const float* ff_b2   = (const float*)d_in[10];
  const float* sc_w    = (const float*)d_in[11];
  const float* sc_b    = (const float*)d_in[12];
  const float* unmap_w = (const float*)d_in[13];
  const float* unmap_b = (const float*)d_in[14];

  float* y_out  = (float*)d_out;                      // (T,B,128)
  float* st_out = y_out + (size_t)Tn * Bn * 128;      // (B,SDn)

  const size_t E = 262144;                            // 2048*128
  unsigned short* Kb0  = (unsigned short*)d_ws;
  unsigned short* Qb0  = Kb0 + E;
  unsigned short* Kt0  = Qb0 + E;
  unsigned short* Vt0  = Kt0 + E;
  unsigned short* Kb1  = Vt0 + E;
  unsigned short* Qb1  = Kb1 + E;
  unsigned short* Kt1  = Qb1 + E;
  unsigned short* Vt1  = Kt1 + E;
  unsigned short* skip0 = Vt1 + E;
  unsigned short* skip1 = skip0 + E;
  unsigned short* attnb = skip1 + E;
  unsigned short* xln1  = attnb + E;
  unsigned short* S0t   = xln1 + E;                   // 2 layers * 8 * 16384
  float* warm_sink = (float*)(S0t + (size_t)2 * 8 * 16384);
  (void)warm_sink;

  prep_kernel<<<528, 256, 0, stream>>>(
      z, state, Wk, Wq, Wv, sc_w, ln_w, ln_b, sc_b,
      Kb0, Qb0, Kt0, Vt0, skip0, S0t);

  attn_kernel<<<384, 256, 0, stream>>>(
      Kb0, Qb0, Vt0, Kt0, S0t, state, attnb, st_out, 0);

  ffln_kernel<<<128, 256, 0, stream>>>(
      attnb, skip0, ff_w1, ff_b1, ff_w2, ff_b2,
      ln_w + 128, ln_b + 128, xln1);

  proj1_kernel<<<512, 256, 0, stream>>>(
      xln1, Wk + 16384, Wq + 16384, Wv + 16384, sc_w + 16384, sc_b + 128,
      Kb1, Qb1, Kt1, Vt1, skip1);

  attn_kernel<<<384, 256, 0, stream>>>(
      Kb1, Qb1, Vt1, Kt1, S0t + (size_t)8 * 16384, state, attnb, st_out, 1);

  ffu_kernel<<<128, 256, 0, stream>>>(
      attnb, skip1, ff_w1 + 16384, ff_b1 + 128, ff_w2 + 16384, ff_b2 + 128,
      unmap_w, unmap_b, y_out);
}